// Round 14
// baseline (135.618 us; speedup 1.0000x reference)
//
#include <hip/hip_runtime.h>

// Problem constants
#define B_     64
#define HW_    96
#define COUT_  96
#define KK_    75          // CIN*KH*KW
#define KPAD   96          // padded K for MFMA (3 x 32)
#define HOUT_  48
#define L_     2304        // 48*48
#define LR_    0.02f
#define DELTA_ -0.4f
#define OUT_ELEMS (B_*COUT_*L_)
#define XS1    2104                 // k1 slab: 3*7*100 f32 + 4 zero-pad slots
#define C2     192                  // k2 positions per block
#define NPART  (B_*12)              // 768 partial rows
#define ROW    (COUT_*KK_ + COUT_)  // 7296 floats: yx[96][75] + yy[96]
#define X2P    99                   // k2 bf16 slab pitch
#define X2N    (33*X2P)             // 3267 u16

typedef __attribute__((ext_vector_type(8))) short short8v;     // 8 bf16
typedef __attribute__((ext_vector_type(4))) float float4v;     // 4 f32 acc
typedef __attribute__((ext_vector_type(4))) unsigned uint4v;   // 16B pack

__device__ __forceinline__ unsigned short f2bf(float f) {  // RNE f32->bf16
  unsigned u = __float_as_uint(f);
  u += 0x7fff + ((u >> 16) & 1);
  return (unsigned short)(u >> 16);
}

// top-2 insert with lax.top_k tiebreak (equal values -> lower channel index)
__device__ __forceinline__ void ins2(float v, int o, float& v1, int& o1,
                                     float& v2, int& o2) {
  bool b1 = (v > v1) || (v == v1 && o < o1);
  bool b2 = (v > v2) || (v == v2 && o < o2);
  if (b1)      { v2 = v1; o2 = o1; v1 = v; o1 = o; }
  else if (b2) { v2 = v;  o2 = o; }
}

// Kernel 0: build stacked bf16 A-matrix [192][96]: rows 0..95 = W, 96..191 = W*|W|.
__global__ __launch_bounds__(256) void k0_prep(const float* __restrict__ w,
                                               unsigned short* __restrict__ wbf) {
  int i = blockIdx.x * 256 + threadIdx.x;
  if (i >= 192 * KPAD) return;
  int row = i / KPAD, k = i - row * KPAD;
  float v = 0.0f;
  if (k < KK_) {
    float ww = w[(row % COUT_) * KK_ + k];
    v = (row < COUT_) ? ww : ww * fabsf(ww);   // sign(w)|w|^2, p=3
  }
  wbf[i] = f2bf(v);
}

// Kernel 1 (v10): r7's lean wave-independent body + r10's LDS-slab gather.
// grid (36, 64) = 2304 blocks = 9/CU (pipelined residency). Block = 64
// consecutive positions; 4 INDEPENDENT waves x 16 positions (one barrier,
// after slab staging). Slab [3][7][100] f32 = 8.4KB (block spans <=2 output
// rows). Gather offsets packed 2x16b -> 12 u32; bfr built per-kt (4 regs);
// acc[12]=48 AGPR; weights streamed from L1-resident global wbf. Natural
// live ~95 regs -> 4+ waves/SIMD under launch_bounds(256,4), no spills.
__global__ __launch_bounds__(256, 4) void k1_mfma(
    const float* __restrict__ x, const unsigned short* __restrict__ wbf,
    float* __restrict__ out, float4* __restrict__ top2)
{
  __shared__ __align__(16) float xs[XS1];                    // 8.4 KB
  const int tid = threadIdx.x;
  const int lane = tid & 63, wq = tid >> 6;
  const int b = blockIdx.y;
  const int bx = blockIdx.x;                  // 0..35
  const int col = lane & 15, g = lane >> 4;
  const float* xb = x + (size_t)b * (3 * HW_ * HW_);

  const int l0 = bx * 64;
  const int oh0 = l0 / HOUT_;
  const int ihbase = 2 * oh0 - 2;

  // stage slab: row = c*7+ihr, ih = ihbase+ihr, iwr = iw+2; OOB & pad -> 0
  #pragma unroll
  for (int i = 0; i < 9; ++i) {
    int idx = tid + i * 256;
    if (idx < XS1) {
      float v = 0.0f;
      if (idx < 2100) {
        int row = idx / 100, iwr = idx - row * 100;
        int c = row / 7, ihr = row - c * 7;
        int ih = ihbase + ihr, iw = iwr - 2;
        if ((unsigned)ih < (unsigned)HW_ && (unsigned)iw < (unsigned)HW_)
          v = xb[(c * HW_ + ih) * HW_ + iw];
      }
      xs[idx] = v;                            // idx 2100..2103 = zero pad
    }
  }

  // per-lane packed gather offsets (lo16 = par0 byteoff, hi16 = par1)
  const int l = l0 + wq * 16 + col;
  const int oh = l / HOUT_, ow = l - oh * HOUT_;
  const int dohr = 2 * (oh - oh0);            // 0 or 2
  unsigned offsPk[12];
  #pragma unroll
  for (int kt = 0; kt < 3; ++kt)
    #pragma unroll
    for (int e2 = 0; e2 < 4; ++e2) {
      unsigned po[2];
      #pragma unroll
      for (int par = 0; par < 2; ++par) {
        int k = kt * 32 + g * 8 + 2 * e2 + par;
        int c = k / 25, r = k - 25 * c, ki = r / 5, kj = r - 5 * ki;
        int fl = (k < KK_) ? (c * 7 + dohr + ki) * 100 + 2 * ow + kj
                           : 2100;            // zeroed pad slot
        po[par] = (unsigned)(fl * 4);
      }
      offsPk[kt * 4 + e2] = po[0] | (po[1] << 16);
    }

  __syncthreads();   // slab ready; waves free-run from here

  // MFMA: acc[mt] covers stacked rows [mt*16,mt*16+16) x this wave's 16 pos.
  float4v acc[12];
  #pragma unroll
  for (int mt = 0; mt < 12; ++mt) acc[mt] = (float4v)(0.0f);
  #pragma unroll
  for (int kt = 0; kt < 3; ++kt) {
    uint4v pk;
    #pragma unroll
    for (int e2 = 0; e2 < 4; ++e2) {
      unsigned o = offsPk[kt * 4 + e2];
      float v0 = *(const float*)((const char*)xs + (o & 0xffffu));
      float v1 = *(const float*)((const char*)xs + (o >> 16));
      pk[e2] = (unsigned)f2bf(v0) | ((unsigned)f2bf(v1) << 16);
    }
    short8v bfr = __builtin_bit_cast(short8v, pk);
    #pragma unroll
    for (int mt = 0; mt < 12; ++mt) {
      short8v afr = *(const short8v*)(
          wbf + ((mt * 16 + col) * KPAD + kt * 32 + g * 8));
      acc[mt] = __builtin_amdgcn_mfma_f32_16x16x32_bf16(
          afr, bfr, acc[mt], 0, 0, 0);
    }
  }

  // W half (rows 0..95): direct store. C/D: col(pos)=lane&15, row=g*4+r (m89).
  #pragma unroll
  for (int mt = 0; mt < 6; ++mt)
    #pragma unroll
    for (int r = 0; r < 4; ++r) {
      const int ch = mt * 16 + g * 4 + r;
      out[((size_t)b * COUT_ + ch) * L_ + l] = acc[mt][r];
    }

  // Wp half (rows 96..191): per-position top-2 over 96 channels.
  float v1 = -3.0e38f, v2 = -3.0e38f;
  int o1 = 0x7fffffff, o2 = 0x7fffffff;
  #pragma unroll
  for (int mt = 6; mt < 12; ++mt)
    #pragma unroll
    for (int r = 0; r < 4; ++r)
      ins2(acc[mt][r], (mt - 6) * 16 + g * 4 + r, v1, o1, v2, o2);
  #pragma unroll
  for (int st = 0; st < 2; ++st) {     // butterfly across the 4 g-groups
    const int d = (st == 0) ? 16 : 32;
    float bv1 = __shfl_xor(v1, d, 64);
    int   bo1 = __shfl_xor(o1, d, 64);
    float bv2 = __shfl_xor(v2, d, 64);
    int   bo2 = __shfl_xor(o2, d, 64);
    ins2(bv1, bo1, v1, o1, v2, o2);
    ins2(bv2, bo2, v1, o1, v2, o2);
  }
  if (g == 0)
    top2[(size_t)b * L_ + l] =
        make_float4(v1, __int_as_float(o1), v2, __int_as_float(o2));
}

// Kernel 2: r13-verbatim: yx/yy via MFMA, 192-pos chunks, 2 blocks/CU.
__global__ __launch_bounds__(256, 2) void k2_gemm(
    const float* __restrict__ x, const float4* __restrict__ top2,
    float* __restrict__ part)
{
  __shared__ __align__(16) unsigned short actS[COUT_ * C2];   // 36 KB
  __shared__ __align__(16) unsigned short preT[COUT_ * C2];   // 36 KB
  __shared__ __align__(16) unsigned short xsb[X2N + 13];      // 6.6 KB bf16 slab
  __shared__ float yyS[COUT_];
  const int tid = threadIdx.x;
  const int b = blockIdx.y;
  const int bx = blockIdx.x;                 // 0..11
  const int l0 = bx * C2;
  const float* xb = x + (size_t)b * (3 * HW_ * HW_);

  // zero act (full) + preT pad rows 75..95 + yy
  {
    float4* a4 = (float4*)actS;
    #pragma unroll
    for (int i = 0; i < 9; ++i) a4[tid + i * 256] = make_float4(0, 0, 0, 0);
    float4* p4 = (float4*)((char*)preT + KK_ * (C2 * 2));   // 21 rows x 384B
    if (tid < 252) {
      p4[2 * tid]     = make_float4(0, 0, 0, 0);
      p4[2 * tid + 1] = make_float4(0, 0, 0, 0);
    }
    if (tid < COUT_) yyS[tid] = 0.0f;
  }

  // stage bf16 x slab: 11 rows per channel, ih = 8bx-2+ihr, iwr = iw+2
  const int ihb2 = 8 * bx - 2;
  #pragma unroll
  for (int i = 0; i < 13; ++i) {
    int idx = tid + i * 256;
    if (idx < X2N) {
      int row = idx / X2P, iwr = idx - row * X2P;
      int c = row / 11, ihr = row - c * 11;
      int ih = ihb2 + ihr, iw = iwr - 2;
      float v = 0.0f;
      if (c < 3 && (unsigned)ih < (unsigned)HW_ && (unsigned)iw < (unsigned)HW_)
        v = xb[(c * HW_ + ih) * HW_ + iw];
      xsb[idx] = f2bf(v);
    }
  }
  __syncthreads();

  // im2col scatter into preT + act + yy (192 of 256 threads)
  if (tid < C2) {
    const int pos = tid;
    const int ohr = pos / HOUT_, ow = pos - ohr * HOUT_;
    const int pblk = pos >> 3, plo = (pos & 7) << 1;
    const unsigned short* xl = xsb + (2 * ohr) * X2P + 2 * ow;
    #pragma unroll
    for (int c = 0; c < 3; ++c)
      #pragma unroll
      for (int ki = 0; ki < 5; ++ki)
        #pragma unroll
        for (int kj = 0; kj < 5; ++kj) {
          int k = c * 25 + ki * 5 + kj;
          unsigned short v = xl[(c * 11 + ki) * X2P + kj];
          *(unsigned short*)((char*)preT +
              k * (C2 * 2) + ((pblk ^ (k & 7)) << 4) + plo) = v;
        }
    float4 t2 = top2[(size_t)b * L_ + l0 + pos];
    int o1 = __float_as_int(t2.y), o2 = __float_as_int(t2.w);
    *(unsigned short*)((char*)actS +
        o1 * (C2 * 2) + ((pblk ^ (o1 & 7)) << 4) + plo) = 0x3F80;  // bf16(1.0)
    *(unsigned short*)((char*)actS +
        o2 * (C2 * 2) + ((pblk ^ (o2 & 7)) << 4) + plo) = f2bf(DELTA_);
    atomicAdd(&yyS[o1], t2.x);
    atomicAdd(&yyS[o2], DELTA_ * t2.z);
  }
  __syncthreads();

  const int lane = tid & 63, w = tid >> 6;
  const int col = lane & 15, g = lane >> 4;
  const int mb = (w >> 1) * 48, nb = (w & 1) * 48;

  float4v acc[3][3];
  #pragma unroll
  for (int mt = 0; mt < 3; ++mt)
    #pragma unroll
    for (int nt = 0; nt < 3; ++nt) acc[mt][nt] = (float4v)(0.0f);

  #pragma unroll
  for (int kt = 0; kt < 6; ++kt) {          // K = 192 positions
    short8v a[3], bf[3];
    #pragma unroll
    for (int mt = 0; mt < 3; ++mt) {
      int row = mb + mt * 16 + col;
      a[mt] = *(const short8v*)((char*)actS + row * (C2 * 2) +
                                (((kt * 4 + g) ^ (row & 7)) << 4));
    }
    #pragma unroll
    for (int nt = 0; nt < 3; ++nt) {
      int row = nb + nt * 16 + col;
      bf[nt] = *(const short8v*)((char*)preT + row * (C2 * 2) +
                                 (((kt * 4 + g) ^ (row & 7)) << 4));
    }
    #pragma unroll
    for (int mt = 0; mt < 3; ++mt)
      #pragma unroll
      for (int nt = 0; nt < 3; ++nt)
        acc[mt][nt] = __builtin_amdgcn_mfma_f32_16x16x32_bf16(
            a[mt], bf[nt], acc[mt][nt], 0, 0, 0);
  }
  __syncthreads();

  float* prow = part + (size_t)(b * 12 + bx) * ROW;
  #pragma unroll
  for (int mt = 0; mt < 3; ++mt)
    #pragma unroll
    for (int nt = 0; nt < 3; ++nt)
      #pragma unroll
      for (int r = 0; r < 4; ++r) {
        int m = mb + mt * 16 + g * 4 + r;
        int n = nb + nt * 16 + col;
        if (n < KK_) prow[m * KK_ + n] = acc[mt][nt][r];
      }
  if (tid < COUT_) prow[COUT_ * KK_ + tid] = yyS[tid];
}

// Kernel 3: reduce 768 partial rows [7296] -> finals[7296]; 4-way p-split.
__global__ __launch_bounds__(256) void k3_reduce(
    const float* __restrict__ part, float* __restrict__ finals)
{
  __shared__ float red[4][64];
  const int e = blockIdx.x * 64 + (threadIdx.x & 63);
  const int seg = threadIdx.x >> 6;
  float s = 0.0f;
  for (int p = seg * (NPART / 4); p < (seg + 1) * (NPART / 4); ++p)
    s += part[(size_t)p * ROW + e];
  red[seg][threadIdx.x & 63] = s;
  __syncthreads();
  if (seg == 0) {
    int ll = threadIdx.x & 63;
    finals[e] = (red[0][ll] + red[1][ll]) + (red[2][ll] + red[3][ll]);
  }
}

// Kernel 4: ds = yx - yy*W; nc = max|ds|; new_W = W + LR*ds/nc.
__global__ __launch_bounds__(256) void k4_finalize(
    const float* __restrict__ w, const float* __restrict__ finals,
    float* __restrict__ outw)
{
  __shared__ float dsS[COUT_ * KK_];
  __shared__ float wmax[4];
  __shared__ float ncS;
  const int tid = threadIdx.x;
  float m = 0.0f;
  for (int i = tid; i < COUT_ * KK_; i += 256) {
    int o = i / KK_;
    float d = finals[i] - finals[COUT_ * KK_ + o] * w[i];
    dsS[i] = d;
    m = fmaxf(m, fabsf(d));
  }
  #pragma unroll
  for (int s = 32; s > 0; s >>= 1) m = fmaxf(m, __shfl_xor(m, s, 64));
  if ((tid & 63) == 0) wmax[tid >> 6] = m;
  __syncthreads();
  if (tid == 0) {
    float n = fmaxf(fmaxf(wmax[0], wmax[1]), fmaxf(wmax[2], wmax[3]));
    ncS = fmaxf(n, 1e-30f);
  }
  __syncthreads();
  const float scale = LR_ / ncS;
  for (int i = tid; i < COUT_ * KK_; i += 256) {
    outw[i] = w[i] + scale * dsS[i];
  }
}

extern "C" void kernel_launch(void* const* d_in, const int* in_sizes, int n_in,
                              void* d_out, int out_size, void* d_ws, size_t ws_size,
                              hipStream_t stream) {
  (void)in_sizes; (void)n_in; (void)out_size; (void)ws_size;
  const float* x = (const float*)d_in[0];   // [64,3,96,96]
  const float* w = (const float*)d_in[1];   // [96,3,5,5]
  float* out  = (float*)d_out;              // conv out [64,96,48,48]
  float* outw = out + OUT_ELEMS;            // new_weight [96,75]

  unsigned short* wbf = (unsigned short*)d_ws;               // [192*96] bf16
  float4* top2 = (float4*)((char*)d_ws + 192 * KPAD * 2);    // [64*2304]
  float*  part = (float*)((char*)top2 + (size_t)B_ * L_ * sizeof(float4)); // [768][7296]
  float*  finals = part + (size_t)NPART * ROW;               // [7296]

  k0_prep   <<<dim3((192 * KPAD + 255) / 256), 256, 0, stream>>>(w, wbf);
  k1_mfma   <<<dim3(36, B_), 256, 0, stream>>>(x, wbf, out, top2);
  k2_gemm   <<<dim3(12, B_), 256, 0, stream>>>(x, top2, part);
  k3_reduce <<<dim3(ROW / 64), 256, 0, stream>>>(part, finals);
  k4_finalize<<<dim3(1), 256, 0, stream>>>(w, finals, outw);
}

// Round 15
// 128.684 us; speedup vs baseline: 1.0539x; 1.0539x over previous
//
#include <hip/hip_runtime.h>

// Problem constants
#define B_     64
#define HW_    96
#define COUT_  96
#define KK_    75          // CIN*KH*KW
#define KPAD   96          // padded K for MFMA (3 x 32)
#define HOUT_  48
#define L_     2304        // 48*48
#define LR_    0.02f
#define DELTA_ -0.4f
#define OUT_ELEMS (B_*COUT_*L_)
#define XPITCH 100                  // k1 slab row pitch
#define XSLOTS 3368                 // 33 rows x 100 + zero pad slots
#define C2     192                  // k2 positions per block
#define NPART  (B_*12)              // 768 partial rows
#define ROW    (COUT_*KK_ + COUT_)  // 7296 floats: yx[96][75] + yy[96]
#define X2P    99                   // k2 bf16 slab pitch
#define X2N    (33*X2P)             // 3267 u16
#define CTP    196                  // cT pitch in floats (49 float4)

typedef __attribute__((ext_vector_type(8))) short short8v;     // 8 bf16
typedef __attribute__((ext_vector_type(4))) float float4v;     // 4 f32 acc
typedef __attribute__((ext_vector_type(4))) unsigned uint4v;   // 16B pack

__device__ __forceinline__ unsigned short f2bf(float f) {  // RNE f32->bf16
  unsigned u = __float_as_uint(f);
  u += 0x7fff + ((u >> 16) & 1);
  return (unsigned short)(u >> 16);
}

// top-2 insert with lax.top_k tiebreak (equal values -> lower channel index)
__device__ __forceinline__ void ins2(float v, int o, float& v1, int& o1,
                                     float& v2, int& o2) {
  bool b1 = (v > v1) || (v == v1 && o < o1);
  bool b2 = (v > v2) || (v == v2 && o < o2);
  if (b1)      { v2 = v1; o2 = o1; v1 = v; o1 = o; }
  else if (b2) { v2 = v;  o2 = o; }
}

// Kernel 0: build stacked bf16 A-matrix [192][96]: rows 0..95 = W, 96..191 = W*|W|.
__global__ __launch_bounds__(256) void k0_prep(const float* __restrict__ w,
                                               unsigned short* __restrict__ wbf) {
  int i = blockIdx.x * 256 + threadIdx.x;
  if (i >= 192 * KPAD) return;
  int row = i / KPAD, k = i - row * KPAD;
  float v = 0.0f;
  if (k < KK_) {
    float ww = w[(row % COUT_) * KK_ + k];
    v = (row < COUT_) ? ww : ww * fabsf(ww);   // sign(w)|w|^2, p=3
  }
  wbf[i] = f2bf(v);
}

// weight-row 16B-block swizzle (bijective within the 12-block row)
__device__ __forceinline__ int wswz(int blk, int row) {
  return (blk < 8) ? (blk ^ (row & 7)) : (blk ^ (row & 3));
}

// Kernel 1 (v11): r13 base + wave-linear dwordx4 out-stores via cT transpose.
// grid (12,64), 4 waves, LDS 50.3KB -> 3 blocks/CU (unchanged). Order: stage;
// T-half MFMA -> top2 (early); W-half MFMA; then 2 passes {acc->cT[48][196]
// (aliases dead wlds+xs), sweep 48 channels as 768B-contiguous dwordx4 runs}.
// Tests the write-granularity theory on the proven 70us base.
__global__ __launch_bounds__(256, 3) void k1_mfma(
    const float* __restrict__ x, const unsigned short* __restrict__ wbf,
    float* __restrict__ out, float4* __restrict__ top2)
{
  __shared__ __align__(16) char ldsRaw[50336];   // wlds 36864 | xs 13472
  unsigned short* wlds = (unsigned short*)ldsRaw;
  float* xs = (float*)(ldsRaw + 36864);
  float* cT = (float*)ldsRaw;                    // alias, live after barrier 2
  const int tid = threadIdx.x;
  const int lane = tid & 63, wq = tid >> 6;
  const int b = blockIdx.y;
  const int bx = blockIdx.x;                  // 0..11
  const int col = lane & 15, g = lane >> 4;
  const float* xb = x + (size_t)b * (3 * HW_ * HW_);

  // stage stacked weights -> LDS (2304 16B chunks, 9 per thread, coalesced)
  #pragma unroll
  for (int i = 0; i < 9; ++i) {
    int id = tid + i * 256;
    int row = id / 12, blk = id - row * 12;
    uint4v v = *(const uint4v*)(wbf + row * KPAD + blk * 8);
    *(uint4v*)((char*)wlds + row * 192 + wswz(blk, row) * 16) = v;
  }

  // stage x slab: row = c*11+ihr, ih = 8bx-2+ihr, iwr = iw+2; OOB & pad -> 0
  const int ihbase = 8 * bx - 2;
  #pragma unroll
  for (int i = 0; i < 14; ++i) {
    int idx = tid + i * 256;
    if (idx < XSLOTS) {
      int row = idx / XPITCH, iwr = idx - row * XPITCH;
      int c = row / 11, ihr = row - c * 11;
      int ih = ihbase + ihr, iw = iwr - 2;
      float v = 0.0f;
      if (c < 3 && (unsigned)ih < (unsigned)HW_ && (unsigned)iw < (unsigned)HW_)
        v = xb[(c * HW_ + ih) * HW_ + iw];
      xs[idx] = v;
    }
  }

  // per-lane absolute byte offsets into xs (invalid k -> zeroed pad slot)
  int offs[12][2];
  {
    const int base_fl = wq * 200 + 2 * col;
    #pragma unroll
    for (int kt = 0; kt < 3; ++kt)
      #pragma unroll
      for (int e2 = 0; e2 < 4; ++e2)
        #pragma unroll
        for (int par = 0; par < 2; ++par) {
          int k = kt * 32 + g * 8 + 2 * e2 + par;
          int c = k / 25, r = k - 25 * c, ki = r / 5, kj = r - 5 * ki;
          int fl = (k < KK_) ? base_fl + (c * 11 + ki) * XPITCH + kj
                             : 33 * XPITCH;          // zeroed pad slot
          offs[kt * 4 + e2][par] = fl * 4;
        }
  }

  __syncthreads();

  // build all 9 B fragments from LDS (pure ds_read+cvt, no guards)
  short8v bfr[3][3];   // [nt][kt]
  #pragma unroll
  for (int nt = 0; nt < 3; ++nt)
    #pragma unroll
    for (int kt = 0; kt < 3; ++kt) {
      uint4v pk;
      #pragma unroll
      for (int e2 = 0; e2 < 4; ++e2) {
        const float* p0 = (const float*)((const char*)xs + offs[kt*4+e2][0]);
        const float* p1 = (const float*)((const char*)xs + offs[kt*4+e2][1]);
        float v0 = p0[nt * 32];
        float v1 = p1[nt * 32];
        pk[e2] = (unsigned)f2bf(v0) | ((unsigned)f2bf(v1) << 16);
      }
      bfr[nt][kt] = __builtin_bit_cast(short8v, pk);
    }

  const int lrow0 = (4 * bx + wq) * 48;
  float4v acc[3][6];

  // ---- T-half FIRST: stacked rows 96..191 = W*|W| (tot -> top-2) ----
  #pragma unroll
  for (int nt = 0; nt < 3; ++nt)
    #pragma unroll
    for (int mt = 0; mt < 6; ++mt) acc[nt][mt] = (float4v)(0.0f);
  #pragma unroll
  for (int kt = 0; kt < 3; ++kt) {
    const int blk = kt * 4 + g;
    #pragma unroll
    for (int mt = 0; mt < 6; ++mt) {
      const int row = 96 + mt * 16 + col;
      short8v afr = *(const short8v*)(
          (const char*)wlds + row * 192 + wswz(blk, row) * 16);
      #pragma unroll
      for (int nt = 0; nt < 3; ++nt)
        acc[nt][mt] = __builtin_amdgcn_mfma_f32_16x16x32_bf16(
            afr, bfr[nt][kt], acc[nt][mt], 0, 0, 0);
    }
  }
  #pragma unroll
  for (int nt = 0; nt < 3; ++nt) {
    float v1 = -3.0e38f, v2 = -3.0e38f;
    int o1 = 0x7fffffff, o2 = 0x7fffffff;
    #pragma unroll
    for (int mt = 0; mt < 6; ++mt)
      #pragma unroll
      for (int r = 0; r < 4; ++r)
        ins2(acc[nt][mt][r], mt * 16 + g * 4 + r, v1, o1, v2, o2);
    #pragma unroll
    for (int st = 0; st < 2; ++st) {
      const int d = (st == 0) ? 16 : 32;
      float bv1 = __shfl_xor(v1, d, 64);
      int   bo1 = __shfl_xor(o1, d, 64);
      float bv2 = __shfl_xor(v2, d, 64);
      int   bo2 = __shfl_xor(o2, d, 64);
      ins2(bv1, bo1, v1, o1, v2, o2);
      ins2(bv2, bo2, v1, o1, v2, o2);
    }
    if (g == 0)
      top2[(size_t)b * L_ + lrow0 + nt * 16 + col] =
          make_float4(v1, __int_as_float(o1), v2, __int_as_float(o2));
  }

  // ---- W-half: stacked rows 0..95 = W (conv out) ----
  #pragma unroll
  for (int nt = 0; nt < 3; ++nt)
    #pragma unroll
    for (int mt = 0; mt < 6; ++mt) acc[nt][mt] = (float4v)(0.0f);
  #pragma unroll
  for (int kt = 0; kt < 3; ++kt) {
    const int blk = kt * 4 + g;
    #pragma unroll
    for (int mt = 0; mt < 6; ++mt) {
      const int row = mt * 16 + col;
      short8v afr = *(const short8v*)(
          (const char*)wlds + row * 192 + wswz(blk, row) * 16);
      #pragma unroll
      for (int nt = 0; nt < 3; ++nt)
        acc[nt][mt] = __builtin_amdgcn_mfma_f32_16x16x32_bf16(
            afr, bfr[nt][kt], acc[nt][mt], 0, 0, 0);
    }
  }
  __syncthreads();   // wlds + xs now dead; cT may be written

  // two transpose-sweep passes: half h covers channels [48h, 48h+48)
  const int blockl = bx * 192;   // block's 192 consecutive positions
  #pragma unroll 1
  for (int h = 0; h < 2; ++h) {
    // acc -> cT: ch-local = (mt-3h)*16+g*4+r, pos = wq*48 + nt*16 + col
    #pragma unroll
    for (int mt = 0; mt < 3; ++mt)
      #pragma unroll
      for (int r = 0; r < 4; ++r) {
        const int chl = mt * 16 + g * 4 + r;
        #pragma unroll
        for (int nt = 0; nt < 3; ++nt)
          cT[chl * CTP + wq * 48 + nt * 16 + col] = acc[nt][h * 3 + mt][r];
      }
    __syncthreads();
    // sweep: 2304 float4s (48 ch x 48 groups); 768B contiguous per channel
    const float4* cT4 = (const float4*)cT;
    #pragma unroll
    for (int i = 0; i < 9; ++i) {
      int idx = tid + i * 256;
      int ch = idx / 48, p4 = idx - ch * 48;
      float4 v = cT4[ch * (CTP / 4) + p4];
      *(float4*)&out[((size_t)b * COUT_ + h * 48 + ch) * L_ + blockl + 4 * p4] = v;
    }
    if (h == 0) __syncthreads();   // before pass B overwrites cT
  }
}

// Kernel 2: r13-verbatim: yx/yy via MFMA, 192-pos chunks, 2 blocks/CU.
__global__ __launch_bounds__(256, 2) void k2_gemm(
    const float* __restrict__ x, const float4* __restrict__ top2,
    float* __restrict__ part)
{
  __shared__ __align__(16) unsigned short actS[COUT_ * C2];   // 36 KB
  __shared__ __align__(16) unsigned short preT[COUT_ * C2];   // 36 KB
  __shared__ __align__(16) unsigned short xsb[X2N + 13];      // 6.6 KB bf16 slab
  __shared__ float yyS[COUT_];
  const int tid = threadIdx.x;
  const int b = blockIdx.y;
  const int bx = blockIdx.x;                 // 0..11
  const int l0 = bx * C2;
  const float* xb = x + (size_t)b * (3 * HW_ * HW_);

  {
    float4* a4 = (float4*)actS;
    #pragma unroll
    for (int i = 0; i < 9; ++i) a4[tid + i * 256] = make_float4(0, 0, 0, 0);
    float4* p4 = (float4*)((char*)preT + KK_ * (C2 * 2));   // 21 rows x 384B
    if (tid < 252) {
      p4[2 * tid]     = make_float4(0, 0, 0, 0);
      p4[2 * tid + 1] = make_float4(0, 0, 0, 0);
    }
    if (tid < COUT_) yyS[tid] = 0.0f;
  }

  const int ihb2 = 8 * bx - 2;
  #pragma unroll
  for (int i = 0; i < 13; ++i) {
    int idx = tid + i * 256;
    if (idx < X2N) {
      int row = idx / X2P, iwr = idx - row * X2P;
      int c = row / 11, ihr = row - c * 11;
      int ih = ihb2 + ihr, iw = iwr - 2;
      float v = 0.0f;
      if (c < 3 && (unsigned)ih < (unsigned)HW_ && (unsigned)iw < (unsigned)HW_)
        v = xb[(c * HW_ + ih) * HW_ + iw];
      xsb[idx] = f2bf(v);
    }
  }
  __syncthreads();

  if (tid < C2) {
    const int pos = tid;
    const int ohr = pos / HOUT_, ow = pos - ohr * HOUT_;
    const int pblk = pos >> 3, plo = (pos & 7) << 1;
    const unsigned short* xl = xsb + (2 * ohr) * X2P + 2 * ow;
    #pragma unroll
    for (int c = 0; c < 3; ++c)
      #pragma unroll
      for (int ki = 0; ki < 5; ++ki)
        #pragma unroll
        for (int kj = 0; kj < 5; ++kj) {
          int k = c * 25 + ki * 5 + kj;
          unsigned short v = xl[(c * 11 + ki) * X2P + kj];
          *(unsigned short*)((char*)preT +
              k * (C2 * 2) + ((pblk ^ (k & 7)) << 4) + plo) = v;
        }
    float4 t2 = top2[(size_t)b * L_ + l0 + pos];
    int o1 = __float_as_int(t2.y), o2 = __float_as_int(t2.w);
    *(unsigned short*)((char*)actS +
        o1 * (C2 * 2) + ((pblk ^ (o1 & 7)) << 4) + plo) = 0x3F80;  // bf16(1.0)
    *(unsigned short*)((char*)actS +
        o2 * (C2 * 2) + ((pblk ^ (o2 & 7)) << 4) + plo) = f2bf(DELTA_);
    atomicAdd(&yyS[o1], t2.x);
    atomicAdd(&yyS[o2], DELTA_ * t2.z);
  }
  __syncthreads();

  const int lane = tid & 63, w = tid >> 6;
  const int col = lane & 15, g = lane >> 4;
  const int mb = (w >> 1) * 48, nb = (w & 1) * 48;

  float4v acc[3][3];
  #pragma unroll
  for (int mt = 0; mt < 3; ++mt)
    #pragma unroll
    for (int nt = 0; nt < 3; ++nt) acc[mt][nt] = (float4v)(0.0f);

  #pragma unroll
  for (int kt = 0; kt < 6; ++kt) {          // K = 192 positions
    short8v a[3], bf[3];
    #pragma unroll
    for (int mt = 0; mt < 3; ++mt) {
      int row = mb + mt * 16 + col;
      a[mt] = *(const short8v*)((char*)actS + row * (C2 * 2) +
                                (((kt * 4 + g) ^ (row & 7)) << 4));
    }
    #pragma unroll
    for (int nt = 0; nt < 3; ++nt) {
      int row = nb + nt * 16 + col;
      bf[nt] = *(const short8v*)((char*)preT + row * (C2 * 2) +
                                 (((kt * 4 + g) ^ (row & 7)) << 4));
    }
    #pragma unroll
    for (int mt = 0; mt < 3; ++mt)
      #pragma unroll
      for (int nt = 0; nt < 3; ++nt)
        acc[mt][nt] = __builtin_amdgcn_mfma_f32_16x16x32_bf16(
            a[mt], bf[nt], acc[mt][nt], 0, 0, 0);
  }
  __syncthreads();

  float* prow = part + (size_t)(b * 12 + bx) * ROW;
  #pragma unroll
  for (int mt = 0; mt < 3; ++mt)
    #pragma unroll
    for (int nt = 0; nt < 3; ++nt)
      #pragma unroll
      for (int r = 0; r < 4; ++r) {
        int m = mb + mt * 16 + g * 4 + r;
        int n = nb + nt * 16 + col;
        if (n < KK_) prow[m * KK_ + n] = acc[mt][nt][r];
      }
  if (tid < COUT_) prow[COUT_ * KK_ + tid] = yyS[tid];
}

// Kernel 3a: partial reduce 768 rows -> tmp[8][7296]. grid (114, 8).
// Each block sums 96 partials (4 thread-segs x 24) for 64 elements.
__global__ __launch_bounds__(256) void k3a_reduce(
    const float* __restrict__ part, float* __restrict__ tmp)
{
  __shared__ float red[4][64];
  const int e = blockIdx.x * 64 + (threadIdx.x & 63);
  const int seg = threadIdx.x >> 6;
  const int p0 = blockIdx.y * 96 + seg * 24;
  float s = 0.0f;
  #pragma unroll 4
  for (int j = 0; j < 24; ++j) s += part[(size_t)(p0 + j) * ROW + e];
  red[seg][threadIdx.x & 63] = s;
  __syncthreads();
  if (seg == 0) {
    int ll = threadIdx.x & 63;
    tmp[(size_t)blockIdx.y * ROW + e] =
        (red[0][ll] + red[1][ll]) + (red[2][ll] + red[3][ll]);
  }
}

// Kernel 3b: fold tmp[8][7296] -> finals[7296]. grid 29.
__global__ __launch_bounds__(256) void k3b_fold(
    const float* __restrict__ tmp, float* __restrict__ finals)
{
  int i = blockIdx.x * 256 + threadIdx.x;
  if (i >= ROW) return;
  float s = 0.0f;
  #pragma unroll
  for (int p = 0; p < 8; ++p) s += tmp[(size_t)p * ROW + i];
  finals[i] = s;
}

// Kernel 4: ds = yx - yy*W; nc = max|ds|; new_W = W + LR*ds/nc.
__global__ __launch_bounds__(256) void k4_finalize(
    const float* __restrict__ w, const float* __restrict__ finals,
    float* __restrict__ outw)
{
  __shared__ float dsS[COUT_ * KK_];
  __shared__ float wmax[4];
  __shared__ float ncS;
  const int tid = threadIdx.x;
  float m = 0.0f;
  for (int i = tid; i < COUT_ * KK_; i += 256) {
    int o = i / KK_;
    float d = finals[i] - finals[COUT_ * KK_ + o] * w[i];
    dsS[i] = d;
    m = fmaxf(m, fabsf(d));
  }
  #pragma unroll
  for (int s = 32; s > 0; s >>= 1) m = fmaxf(m, __shfl_xor(m, s, 64));
  if ((tid & 63) == 0) wmax[tid >> 6] = m;
  __syncthreads();
  if (tid == 0) {
    float n = fmaxf(fmaxf(wmax[0], wmax[1]), fmaxf(wmax[2], wmax[3]));
    ncS = fmaxf(n, 1e-30f);
  }
  __syncthreads();
  const float scale = LR_ / ncS;
  for (int i = tid; i < COUT_ * KK_; i += 256) {
    outw[i] = w[i] + scale * dsS[i];
  }
}

extern "C" void kernel_launch(void* const* d_in, const int* in_sizes, int n_in,
                              void* d_out, int out_size, void* d_ws, size_t ws_size,
                              hipStream_t stream) {
  (void)in_sizes; (void)n_in; (void)out_size; (void)ws_size;
  const float* x = (const float*)d_in[0];   // [64,3,96,96]
  const float* w = (const float*)d_in[1];   // [96,3,5,5]
  float* out  = (float*)d_out;              // conv out [64,96,48,48]
  float* outw = out + OUT_ELEMS;            // new_weight [96,75]

  unsigned short* wbf = (unsigned short*)d_ws;               // [192*96] bf16
  float4* top2 = (float4*)((char*)d_ws + 192 * KPAD * 2);    // [64*2304]
  float*  part = (float*)((char*)top2 + (size_t)B_ * L_ * sizeof(float4)); // [768][7296]
  float*  finals = part + (size_t)NPART * ROW;               // [7296]
  float*  tmp    = finals + ROW;                             // [8][7296]

  k0_prep   <<<dim3((192 * KPAD + 255) / 256), 256, 0, stream>>>(w, wbf);
  k1_mfma   <<<dim3(12, B_), 256, 0, stream>>>(x, wbf, out, top2);
  k2_gemm   <<<dim3(12, B_), 256, 0, stream>>>(x, top2, part);
  k3a_reduce<<<dim3(114, 8), 256, 0, stream>>>(part, tmp);
  k3b_fold  <<<dim3(29), 256, 0, stream>>>(tmp, finals);
  k4_finalize<<<dim3(1), 256, 0, stream>>>(w, finals, outw);
}

// Round 16
// 110.969 us; speedup vs baseline: 1.2221x; 1.1596x over previous
//
#include <hip/hip_runtime.h>

// Problem constants
#define B_     64
#define HW_    96
#define COUT_  96
#define KK_    75          // CIN*KH*KW
#define KPAD   96          // padded K for MFMA (3 x 32)
#define HOUT_  48
#define L_     2304        // 48*48
#define LR_    0.02f
#define DELTA_ -0.4f
#define OUT_ELEMS (B_*COUT_*L_)
#define XPITCH 100                  // k1 slab row pitch
#define XSLOTS 3368                 // 33 rows x 100 + zero pad slots
#define C2     192                  // k2 positions per block
#define NPART  (B_*12)              // 768 partial rows
#define ROW    (COUT_*KK_ + COUT_)  // 7296 floats: yx[96][75] + yy[96]
#define X2P    99                   // k2 bf16 slab pitch
#define X2N    (33*X2P)             // 3267 u16
#define CTP    196                  // cT pitch in floats (49 float4)

typedef __attribute__((ext_vector_type(8))) short short8v;     // 8 bf16
typedef __attribute__((ext_vector_type(4))) float float4v;     // 4 f32 acc
typedef __attribute__((ext_vector_type(4))) unsigned uint4v;   // 16B pack

__device__ __forceinline__ unsigned short f2bf(float f) {  // RNE f32->bf16
  unsigned u = __float_as_uint(f);
  u += 0x7fff + ((u >> 16) & 1);
  return (unsigned short)(u >> 16);
}

// top-2 insert with lax.top_k tiebreak (equal values -> lower channel index)
__device__ __forceinline__ void ins2(float v, int o, float& v1, int& o1,
                                     float& v2, int& o2) {
  bool b1 = (v > v1) || (v == v1 && o < o1);
  bool b2 = (v > v2) || (v == v2 && o < o2);
  if (b1)      { v2 = v1; o2 = o1; v1 = v; o1 = o; }
  else if (b2) { v2 = v;  o2 = o; }
}

// Kernel 0: build stacked bf16 A-matrix [192][96]: rows 0..95 = W, 96..191 = W*|W|.
__global__ __launch_bounds__(256) void k0_prep(const float* __restrict__ w,
                                               unsigned short* __restrict__ wbf) {
  int i = blockIdx.x * 256 + threadIdx.x;
  if (i >= 192 * KPAD) return;
  int row = i / KPAD, k = i - row * KPAD;
  float v = 0.0f;
  if (k < KK_) {
    float ww = w[(row % COUT_) * KK_ + k];
    v = (row < COUT_) ? ww : ww * fabsf(ww);   // sign(w)|w|^2, p=3
  }
  wbf[i] = f2bf(v);
}

// weight-row 16B-block swizzle (bijective within the 12-block row)
__device__ __forceinline__ int wswz(int blk, int row) {
  return (blk < 8) ? (blk ^ (row & 7)) : (blk ^ (row & 3));
}

// Kernel 1 (v12): r13 base; W-half stores via 6 register-light cT passes.
// grid (12,64), 4 waves, LDS 50.3KB -> 3 blocks/CU. T-half (72 AGPR, proven
// spill-free shape) runs first -> top2. Then per 16-channel pass: 9 MFMAs
// into acc3[3] (12 AGPR), bounce through cT[16][196] aliased on the DEAD xs
// region only (wlds intact for A-frags), barrier, sweep 768B-contiguous
// float4 runs. Tests write-granularity with no register bomb.
__global__ __launch_bounds__(256, 3) void k1_mfma(
    const float* __restrict__ x, const unsigned short* __restrict__ wbf,
    float* __restrict__ out, float4* __restrict__ top2)
{
  __shared__ __align__(16) char ldsRaw[50336];   // wlds 36864 | xs 13472
  unsigned short* wlds = (unsigned short*)ldsRaw;
  float* xs = (float*)(ldsRaw + 36864);
  float* cT = xs;                                // alias xs AFTER bfr built
  const int tid = threadIdx.x;
  const int lane = tid & 63, wq = tid >> 6;
  const int b = blockIdx.y;
  const int bx = blockIdx.x;                  // 0..11
  const int col = lane & 15, g = lane >> 4;
  const float* xb = x + (size_t)b * (3 * HW_ * HW_);

  // stage stacked weights -> LDS (2304 16B chunks, 9 per thread, coalesced)
  #pragma unroll
  for (int i = 0; i < 9; ++i) {
    int id = tid + i * 256;
    int row = id / 12, blk = id - row * 12;
    uint4v v = *(const uint4v*)(wbf + row * KPAD + blk * 8);
    *(uint4v*)((char*)wlds + row * 192 + wswz(blk, row) * 16) = v;
  }

  // stage x slab: row = c*11+ihr, ih = 8bx-2+ihr, iwr = iw+2; OOB & pad -> 0
  const int ihbase = 8 * bx - 2;
  #pragma unroll
  for (int i = 0; i < 14; ++i) {
    int idx = tid + i * 256;
    if (idx < XSLOTS) {
      int row = idx / XPITCH, iwr = idx - row * XPITCH;
      int c = row / 11, ihr = row - c * 11;
      int ih = ihbase + ihr, iw = iwr - 2;
      float v = 0.0f;
      if (c < 3 && (unsigned)ih < (unsigned)HW_ && (unsigned)iw < (unsigned)HW_)
        v = xb[(c * HW_ + ih) * HW_ + iw];
      xs[idx] = v;
    }
  }

  // per-lane absolute byte offsets into xs (invalid k -> zeroed pad slot)
  int offs[12][2];
  {
    const int base_fl = wq * 200 + 2 * col;
    #pragma unroll
    for (int kt = 0; kt < 3; ++kt)
      #pragma unroll
      for (int e2 = 0; e2 < 4; ++e2)
        #pragma unroll
        for (int par = 0; par < 2; ++par) {
          int k = kt * 32 + g * 8 + 2 * e2 + par;
          int c = k / 25, r = k - 25 * c, ki = r / 5, kj = r - 5 * ki;
          int fl = (k < KK_) ? base_fl + (c * 11 + ki) * XPITCH + kj
                             : 33 * XPITCH;          // zeroed pad slot
          offs[kt * 4 + e2][par] = fl * 4;
        }
  }

  __syncthreads();

  // build all 9 B fragments from LDS (pure ds_read+cvt, no guards)
  short8v bfr[3][3];   // [nt][kt]
  #pragma unroll
  for (int nt = 0; nt < 3; ++nt)
    #pragma unroll
    for (int kt = 0; kt < 3; ++kt) {
      uint4v pk;
      #pragma unroll
      for (int e2 = 0; e2 < 4; ++e2) {
        const float* p0 = (const float*)((const char*)xs + offs[kt*4+e2][0]);
        const float* p1 = (const float*)((const char*)xs + offs[kt*4+e2][1]);
        float v0 = p0[nt * 32];
        float v1 = p1[nt * 32];
        pk[e2] = (unsigned)f2bf(v0) | ((unsigned)f2bf(v1) << 16);
      }
      bfr[nt][kt] = __builtin_bit_cast(short8v, pk);
    }

  const int lrow0 = (4 * bx + wq) * 48;

  // ---- T-half first: stacked rows 96..191 = W*|W| (tot -> top-2) ----
  {
    float4v acc[3][6];
    #pragma unroll
    for (int nt = 0; nt < 3; ++nt)
      #pragma unroll
      for (int mt = 0; mt < 6; ++mt) acc[nt][mt] = (float4v)(0.0f);
    #pragma unroll
    for (int kt = 0; kt < 3; ++kt) {
      const int blk = kt * 4 + g;
      #pragma unroll
      for (int mt = 0; mt < 6; ++mt) {
        const int row = 96 + mt * 16 + col;
        short8v afr = *(const short8v*)(
            (const char*)wlds + row * 192 + wswz(blk, row) * 16);
        #pragma unroll
        for (int nt = 0; nt < 3; ++nt)
          acc[nt][mt] = __builtin_amdgcn_mfma_f32_16x16x32_bf16(
              afr, bfr[nt][kt], acc[nt][mt], 0, 0, 0);
      }
    }
    #pragma unroll
    for (int nt = 0; nt < 3; ++nt) {
      float v1 = -3.0e38f, v2 = -3.0e38f;
      int o1 = 0x7fffffff, o2 = 0x7fffffff;
      #pragma unroll
      for (int mt = 0; mt < 6; ++mt)
        #pragma unroll
        for (int r = 0; r < 4; ++r)
          ins2(acc[nt][mt][r], mt * 16 + g * 4 + r, v1, o1, v2, o2);
      #pragma unroll
      for (int st = 0; st < 2; ++st) {
        const int d = (st == 0) ? 16 : 32;
        float bv1 = __shfl_xor(v1, d, 64);
        int   bo1 = __shfl_xor(o1, d, 64);
        float bv2 = __shfl_xor(v2, d, 64);
        int   bo2 = __shfl_xor(o2, d, 64);
        ins2(bv1, bo1, v1, o1, v2, o2);
        ins2(bv2, bo2, v1, o1, v2, o2);
      }
      if (g == 0)
        top2[(size_t)b * L_ + lrow0 + nt * 16 + col] =
            make_float4(v1, __int_as_float(o1), v2, __int_as_float(o2));
    }
  }

  __syncthreads();   // all waves done with xs (bfr built) -> cT may alias it

  // ---- W-half: 6 passes of 16 channels, cT bounce, coalesced sweeps ----
  const int blockl = bx * 192;   // block's 192 consecutive positions
  #pragma unroll 1
  for (int mt = 0; mt < 6; ++mt) {
    float4v a0 = (float4v)(0.0f), a1 = (float4v)(0.0f), a2 = (float4v)(0.0f);
    #pragma unroll
    for (int kt = 0; kt < 3; ++kt) {
      const int blk = kt * 4 + g;
      const int row = mt * 16 + col;
      short8v afr = *(const short8v*)(
          (const char*)wlds + row * 192 + wswz(blk, row) * 16);
      a0 = __builtin_amdgcn_mfma_f32_16x16x32_bf16(afr, bfr[0][kt], a0, 0, 0, 0);
      a1 = __builtin_amdgcn_mfma_f32_16x16x32_bf16(afr, bfr[1][kt], a1, 0, 0, 0);
      a2 = __builtin_amdgcn_mfma_f32_16x16x32_bf16(afr, bfr[2][kt], a2, 0, 0, 0);
    }
    // cT[chl][pos]: chl = g*4+r, pos = wq*48 + nt*16 + col (2-way banks, free)
    #pragma unroll
    for (int r = 0; r < 4; ++r) {
      const int chl = g * 4 + r;
      float* cp = cT + chl * CTP + wq * 48 + col;
      cp[0]  = a0[r];
      cp[16] = a1[r];
      cp[32] = a2[r];
    }
    __syncthreads();
    // sweep: 768 float4s (16 ch x 48 groups); 768B contiguous per channel
    const float4* cT4 = (const float4*)cT;
    #pragma unroll
    for (int i = 0; i < 3; ++i) {
      int idx = tid + i * 256;
      int ch = idx / 48, p4 = idx - ch * 48;
      float4 v = cT4[ch * (CTP / 4) + p4];
      *(float4*)&out[((size_t)b * COUT_ + mt * 16 + ch) * L_ + blockl + 4 * p4] = v;
    }
    if (mt < 5) __syncthreads();   // sweep reads done before next pass writes
  }
}

// Kernel 2: r13-verbatim: yx/yy via MFMA, 192-pos chunks, 2 blocks/CU.
__global__ __launch_bounds__(256, 2) void k2_gemm(
    const float* __restrict__ x, const float4* __restrict__ top2,
    float* __restrict__ part)
{
  __shared__ __align__(16) unsigned short actS[COUT_ * C2];   // 36 KB
  __shared__ __align__(16) unsigned short preT[COUT_ * C2];   // 36 KB
  __shared__ __align__(16) unsigned short xsb[X2N + 13];      // 6.6 KB bf16 slab
  __shared__ float yyS[COUT_];
  const int tid = threadIdx.x;
  const int b = blockIdx.y;
  const int bx = blockIdx.x;                 // 0..11
  const int l0 = bx * C2;
  const float* xb = x + (size_t)b * (3 * HW_ * HW_);

  {
    float4* a4 = (float4*)actS;
    #pragma unroll
    for (int i = 0; i < 9; ++i) a4[tid + i * 256] = make_float4(0, 0, 0, 0);
    float4* p4 = (float4*)((char*)preT + KK_ * (C2 * 2));   // 21 rows x 384B
    if (tid < 252) {
      p4[2 * tid]     = make_float4(0, 0, 0, 0);
      p4[2 * tid + 1] = make_float4(0, 0, 0, 0);
    }
    if (tid < COUT_) yyS[tid] = 0.0f;
  }

  const int ihb2 = 8 * bx - 2;
  #pragma unroll
  for (int i = 0; i < 13; ++i) {
    int idx = tid + i * 256;
    if (idx < X2N) {
      int row = idx / X2P, iwr = idx - row * X2P;
      int c = row / 11, ihr = row - c * 11;
      int ih = ihb2 + ihr, iw = iwr - 2;
      float v = 0.0f;
      if (c < 3 && (unsigned)ih < (unsigned)HW_ && (unsigned)iw < (unsigned)HW_)
        v = xb[(c * HW_ + ih) * HW_ + iw];
      xsb[idx] = f2bf(v);
    }
  }
  __syncthreads();

  if (tid < C2) {
    const int pos = tid;
    const int ohr = pos / HOUT_, ow = pos - ohr * HOUT_;
    const int pblk = pos >> 3, plo = (pos & 7) << 1;
    const unsigned short* xl = xsb + (2 * ohr) * X2P + 2 * ow;
    #pragma unroll
    for (int c = 0; c < 3; ++c)
      #pragma unroll
      for (int ki = 0; ki < 5; ++ki)
        #pragma unroll
        for (int kj = 0; kj < 5; ++kj) {
          int k = c * 25 + ki * 5 + kj;
          unsigned short v = xl[(c * 11 + ki) * X2P + kj];
          *(unsigned short*)((char*)preT +
              k * (C2 * 2) + ((pblk ^ (k & 7)) << 4) + plo) = v;
        }
    float4 t2 = top2[(size_t)b * L_ + l0 + pos];
    int o1 = __float_as_int(t2.y), o2 = __float_as_int(t2.w);
    *(unsigned short*)((char*)actS +
        o1 * (C2 * 2) + ((pblk ^ (o1 & 7)) << 4) + plo) = 0x3F80;  // bf16(1.0)
    *(unsigned short*)((char*)actS +
        o2 * (C2 * 2) + ((pblk ^ (o2 & 7)) << 4) + plo) = f2bf(DELTA_);
    atomicAdd(&yyS[o1], t2.x);
    atomicAdd(&yyS[o2], DELTA_ * t2.z);
  }
  __syncthreads();

  const int lane = tid & 63, w = tid >> 6;
  const int col = lane & 15, g = lane >> 4;
  const int mb = (w >> 1) * 48, nb = (w & 1) * 48;

  float4v acc[3][3];
  #pragma unroll
  for (int mt = 0; mt < 3; ++mt)
    #pragma unroll
    for (int nt = 0; nt < 3; ++nt) acc[mt][nt] = (float4v)(0.0f);

  #pragma unroll
  for (int kt = 0; kt < 6; ++kt) {          // K = 192 positions
    short8v a[3], bf[3];
    #pragma unroll
    for (int mt = 0; mt < 3; ++mt) {
      int row = mb + mt * 16 + col;
      a[mt] = *(const short8v*)((char*)actS + row * (C2 * 2) +
                                (((kt * 4 + g) ^ (row & 7)) << 4));
    }
    #pragma unroll
    for (int nt = 0; nt < 3; ++nt) {
      int row = nb + nt * 16 + col;
      bf[nt] = *(const short8v*)((char*)preT + row * (C2 * 2) +
                                 (((kt * 4 + g) ^ (row & 7)) << 4));
    }
    #pragma unroll
    for (int mt = 0; mt < 3; ++mt)
      #pragma unroll
      for (int nt = 0; nt < 3; ++nt)
        acc[mt][nt] = __builtin_amdgcn_mfma_f32_16x16x32_bf16(
            a[mt], bf[nt], acc[mt][nt], 0, 0, 0);
  }
  __syncthreads();

  float* prow = part + (size_t)(b * 12 + bx) * ROW;
  #pragma unroll
  for (int mt = 0; mt < 3; ++mt)
    #pragma unroll
    for (int nt = 0; nt < 3; ++nt)
      #pragma unroll
      for (int r = 0; r < 4; ++r) {
        int m = mb + mt * 16 + g * 4 + r;
        int n = nb + nt * 16 + col;
        if (n < KK_) prow[m * KK_ + n] = acc[mt][nt][r];
      }
  if (tid < COUT_) prow[COUT_ * KK_ + tid] = yyS[tid];
}

// Kernel 3a: partial reduce 768 rows -> tmp[8][7296]. grid (114, 8).
__global__ __launch_bounds__(256) void k3a_reduce(
    const float* __restrict__ part, float* __restrict__ tmp)
{
  __shared__ float red[4][64];
  const int e = blockIdx.x * 64 + (threadIdx.x & 63);
  const int seg = threadIdx.x >> 6;
  const int p0 = blockIdx.y * 96 + seg * 24;
  float s = 0.0f;
  #pragma unroll 4
  for (int j = 0; j < 24; ++j) s += part[(size_t)(p0 + j) * ROW + e];
  red[seg][threadIdx.x & 63] = s;
  __syncthreads();
  if (seg == 0) {
    int ll = threadIdx.x & 63;
    tmp[(size_t)blockIdx.y * ROW + e] =
        (red[0][ll] + red[1][ll]) + (red[2][ll] + red[3][ll]);
  }
}

// Kernel 3b: fold tmp[8][7296] -> finals[7296]. grid 29.
__global__ __launch_bounds__(256) void k3b_fold(
    const float* __restrict__ tmp, float* __restrict__ finals)
{
  int i = blockIdx.x * 256 + threadIdx.x;
  if (i >= ROW) return;
  float s = 0.0f;
  #pragma unroll
  for (int p = 0; p < 8; ++p) s += tmp[(size_t)p * ROW + i];
  finals[i] = s;
}

// Kernel 4: ds = yx - yy*W; nc = max|ds|; new_W = W + LR*ds/nc.
__global__ __launch_bounds__(256) void k4_finalize(
    const float* __restrict__ w, const float* __restrict__ finals,
    float* __restrict__ outw)
{
  __shared__ float dsS[COUT_ * KK_];
  __shared__ float wmax[4];
  __shared__ float ncS;
  const int tid = threadIdx.x;
  float m = 0.0f;
  for (int i = tid; i < COUT_ * KK_; i += 256) {
    int o = i / KK_;
    float d = finals[i] - finals[COUT_ * KK_ + o] * w[i];
    dsS[i] = d;
    m = fmaxf(m, fabsf(d));
  }
  #pragma unroll
  for (int s = 32; s > 0; s >>= 1) m = fmaxf(m, __shfl_xor(m, s, 64));
  if ((tid & 63) == 0) wmax[tid >> 6] = m;
  __syncthreads();
  if (tid == 0) {
    float n = fmaxf(fmaxf(wmax[0], wmax[1]), fmaxf(wmax[2], wmax[3]));
    ncS = fmaxf(n, 1e-30f);
  }
  __syncthreads();
  const float scale = LR_ / ncS;
  for (int i = tid; i < COUT_ * KK_; i += 256) {
    outw[i] = w[i] + scale * dsS[i];
  }
}

extern "C" void kernel_launch(void* const* d_in, const int* in_sizes, int n_in,
                              void* d_out, int out_size, void* d_ws, size_t ws_size,
                              hipStream_t stream) {
  (void)in_sizes; (void)n_in; (void)out_size; (void)ws_size;
  const float* x = (const float*)d_in[0];   // [64,3,96,96]
  const float* w = (const float*)d_in[1];   // [96,3,5,5]
  float* out  = (float*)d_out;              // conv out [64,96,48,48]
  float* outw = out + OUT_ELEMS;            // new_weight [96,75]

  unsigned short* wbf = (unsigned short*)d_ws;               // [192*96] bf16
  float4* top2 = (float4*)((char*)d_ws + 192 * KPAD * 2);    // [64*2304]
  float*  part = (float*)((char*)top2 + (size_t)B_ * L_ * sizeof(float4)); // [768][7296]
  float*  finals = part + (size_t)NPART * ROW;               // [7296]
  float*  tmp    = finals + ROW;                             // [8][7296]

  k0_prep   <<<dim3((192 * KPAD + 255) / 256), 256, 0, stream>>>(w, wbf);
  k1_mfma   <<<dim3(12, B_), 256, 0, stream>>>(x, wbf, out, top2);
  k2_gemm   <<<dim3(12, B_), 256, 0, stream>>>(x, top2, part);
  k3a_reduce<<<dim3(114, 8), 256, 0, stream>>>(part, tmp);
  k3b_fold  <<<dim3(29), 256, 0, stream>>>(tmp, finals);
  k4_finalize<<<dim3(1), 256, 0, stream>>>(w, finals, outw);
}